// Round 9
// baseline (208.095 us; speedup 1.0000x reference)
//
#include <hip/hip_runtime.h>
#include <math.h>

#define H 64
#define W 64
#define C 128
#define NB 8
#define COUT 128
#define HWi 4096
#define NKC 36
#define PADu 40          // LDS row pitch in ushorts (80B = 5 superbanks)
#define NBLK 512u        // k_fused grid; 2 blocks/CU vs 4/CU capacity -> all co-resident

typedef __attribute__((ext_vector_type(8))) short short8;
typedef __attribute__((ext_vector_type(8))) unsigned short ushort8;
typedef __attribute__((ext_vector_type(4))) unsigned int uint4v;
typedef __attribute__((ext_vector_type(4))) float f32x4;

__device__ __forceinline__ unsigned short f2bf(float f){
    unsigned u = __float_as_uint(f);
    unsigned r = (u + 0x7FFFu + ((u >> 16) & 1u)) >> 16;
    return (unsigned short)r;
}
__device__ __forceinline__ float bf2f(unsigned short u){
    return __uint_as_float(((unsigned)u) << 16);
}
__device__ __forceinline__ unsigned cvtpk_bf16(float lo, float hi){
    unsigned r;
    asm("v_cvt_pk_bf16_f32 %0, %1, %2" : "=v"(r) : "v"(lo), "v"(hi));
    return r;
}

// ---------- k_pre: fused x-transpose + weight prep + psum/bar zero ----------
// blocks [0,528): x NCHW fp32 -> zero-padded NHWC bf16 [8][66][66][128], XCD-affine batch=bid&7
// blocks [528,1250): wAv [kc][q4][r128][j8], w27A [kc][q4][m32][t8], biasom, psum=0, bar=0
__global__ void k_pre(const float* __restrict__ x, unsigned short* __restrict__ xTp,
                      const float* __restrict__ w_reg, const float* __restrict__ w_off,
                      const float* __restrict__ w_mod, const float* __restrict__ b_off,
                      const float* __restrict__ b_mod,
                      unsigned short* __restrict__ wAv, unsigned short* __restrict__ w27A,
                      float* __restrict__ biasom, float* __restrict__ psum,
                      unsigned* __restrict__ bar){
    int tid = threadIdx.x;
    if (blockIdx.x >= 528){
        int i = (blockIdx.x - 528) * 256 + tid;
        if (i < 147456){
            int kc = i >> 12, rem = i & 4095;
            int q = rem >> 10, r = (rem >> 3) & 127, j = rem & 7;
            int kk = kc * 32 + q * 8 + j, k = kk >> 7, c = kk & 127;
            wAv[i] = f2bf(w_reg[r * 1152 + c * 9 + k]);
        } else if (i < 147456 + 36864){
            int j2 = i - 147456;
            int kc = j2 >> 10, rem = j2 & 1023;
            int q = rem >> 8, m = (rem >> 3) & 31, t = rem & 7;
            int kkl = q * 8 + t;
            int kk = kc * 32 + kkl, k = kk >> 7, c = kk & 127;
            float v = 0.f;
            if (m < 18) v = w_off[m * 1152 + c * 9 + k];
            else if (m < 27) v = w_mod[(m - 18) * 1152 + c * 9 + k];
            w27A[j2] = f2bf(v);
        } else if (i < 147456 + 36864 + 32){
            int m = i - 147456 - 36864;
            biasom[m] = (m < 18) ? b_off[m] : (m < 27 ? b_mod[m - 18] : 0.f);
        } else if (i < 147456 + 36864 + 32 + 257){
            int z = i - (147456 + 36864 + 32);
            if (z < 256) psum[z] = 0.f;
            else *bar = 0u;   // stream-ordered before k_fused; kernel boundary flushes
        }
        return;
    }
    int bidx = blockIdx.x;
    int b = bidx & 7, hp = bidx >> 3;       // XCD-affine: batch = bid%8
    unsigned short* row = xTp + (size_t)(b * 66 + hp) * 66 * 128;
    if (hp == 0 || hp == 65){
        ushort8 z = {0,0,0,0,0,0,0,0};
        for (int i = tid; i < 66 * 128 / 8; i += 256) ((ushort8*)row)[i] = z;
        return;
    }
    int h = hp - 1;
    __shared__ unsigned short s[64 * 136];
    int w = tid & 63, c0 = tid >> 6;
    for (int cc = 0; cc < 128; cc += 4){
        int c = cc + c0;
        s[w * 136 + c] = f2bf(x[(size_t)(b * 128 + c) * HWi + h * 64 + w]);
    }
    __syncthreads();
    if (tid < 32){
        ushort8 z = {0,0,0,0,0,0,0,0};
        int wp = (tid < 16) ? 0 : 65;
        int sg = tid & 15;
        *(ushort8*)(row + wp * 128 + sg * 8) = z;
    }
    for (int it = tid; it < 1024; it += 256){
        int w2 = it >> 4, sg = it & 15;
        *(ushort8*)(row + (w2 + 1) * 128 + sg * 8) = *(const ushort8*)(s + w2 * 136 + sg * 8);
    }
}

// ---------- k_fused: 27-conv + deformable GEMM + BN/ReLU, software grid barrier ----------
// Round 7/8's cooperative launch never executed under graph capture (out stayed
// memset-0 -> absmax == max|ref|). Same fused structure, but PLAIN launch + an
// arrive-and-spin barrier: 512 blocks = 2/CU vs 4/CU capacity -> all co-resident.
__global__ __launch_bounds__(512, 4) void k_fused(const unsigned short* __restrict__ xTp,
        const unsigned short* __restrict__ w27A, const float* __restrict__ biasom,
        const unsigned short* __restrict__ wAv, const float* __restrict__ b_reg,
        const float* __restrict__ gamma, const float* __restrict__ beta,
        float* __restrict__ out, float* __restrict__ psum, unsigned* __restrict__ bar){
    __shared__ char smem[38912];
    int tid = threadIdx.x;
    // XCD-affine swizzle: 512 blocks = 8 batches x 64 rows; batch (bid&7) -> XCD (bid&7)
    int lb = (blockIdx.x & 7) * 64 + (blockIdx.x >> 3);
    int n0 = lb * 64;
    int b = n0 >> 12, h = (n0 >> 6) & 63;

    // ================= Phase 1: offset/mod conv, K split across 2 groups =================
    {
        int grp = tid >> 8, gt = tid & 255;
        unsigned short* pB = (unsigned short*)(smem + grp * 10240);   // [2][64*PADu] per grp
        int wvg = gt >> 6, lane = gt & 63, quad = lane >> 4, l16 = lane & 15;
        int nl = gt >> 2, sg = gt & 3;
        f32x4 acc0 = {0.f,0.f,0.f,0.f}, acc1 = {0.f,0.f,0.f,0.f};
        int kc0 = grp * 18;
        auto p1load = [&](int i, ushort8& B8){
            int kc = kc0 + i;
            int k = kc >> 2, cb = (kc & 3) << 5;
            int ki = k / 3, kj = k - ki * 3;
            int rowi = (b * 66 + h + ki) * 66 + (nl + kj);
            B8 = *(const ushort8*)(xTp + (size_t)rowi * 128 + cb + sg * 8);
        };
        auto p1body = [&](int i, ushort8& B8){
            int p = i & 1;
            int kc = kc0 + i;
            const unsigned short* wj = w27A + kc * 1024 + quad * 256;
            short8 a0 = *(const short8*)(wj + l16 * 8);
            short8 a1 = *(const short8*)(wj + (16 + l16) * 8);
            *(ushort8*)(pB + p * 2560 + nl * PADu + sg * 8) = B8;
            if (i + 2 < 18) p1load(i + 2, B8);   // 2-deep prefetch
            __syncthreads();
            short8 bfrag = *(const short8*)(pB + p * 2560 + (wvg * 16 + l16) * PADu + quad * 8);
            acc0 = __builtin_amdgcn_mfma_f32_16x16x32_bf16(a0, bfrag, acc0, 0, 0, 0);
            acc1 = __builtin_amdgcn_mfma_f32_16x16x32_bf16(a1, bfrag, acc1, 0, 0, 0);
        };
        ushort8 rB0, rB1;
        p1load(0, rB0);
        p1load(1, rB1);
        for (int ih = 0; ih < 9; ih++){
            p1body(ih * 2,     rB0);
            p1body(ih * 2 + 1, rB1);
        }
        float* s_red = (float*)(smem + 20480);     // [64][32] fp32
        int npx = wvg * 16 + l16;
        if (grp == 1){
            #pragma unroll
            for (int t = 0; t < 2; t++){
                f32x4 a = t ? acc1 : acc0;
                #pragma unroll
                for (int r = 0; r < 4; r++)
                    s_red[npx * 32 + t * 16 + quad * 4 + r] = a[r];
            }
        }
        __syncthreads();
        if (grp == 0){
            unsigned short* s_OM = (unsigned short*)smem;  // [64][32] bf16 at [0,4096)
            #pragma unroll
            for (int t = 0; t < 2; t++){
                f32x4 a = t ? acc1 : acc0;
                #pragma unroll
                for (int r = 0; r < 4; r++){
                    int oc = t * 16 + quad * 4 + r;
                    float v = a[r] + s_red[npx * 32 + oc] + biasom[oc];
                    if (oc >= 18) v = 2.f / (1.f + expf(-v));
                    s_OM[npx * 32 + oc] = f2bf(v);
                }
            }
        }
        __syncthreads();
    }

    // ================= Phase 2: deformable sampling + 128-out GEMM (paired kc) ============
    unsigned short* sB = (unsigned short*)smem;              // [2][2][64*PADu] = 20480 B
    int*   s_a0 = (int*)(smem + 20480);                      // [4][576] = 9216 B
    float* s_w0 = (float*)(smem + 29696);                    // [4][576] = 9216 B (ends 38912)
    const unsigned short* s_OM = (const unsigned short*)smem;  // alias (prologue only)

    for (int idx = tid; idx < 576; idx += 512){
        int k = idx >> 6, px_ = idx & 63;
        float dy = bf2f(s_OM[px_ * 32 + 2 * k]);
        float dx = bf2f(s_OM[px_ * 32 + 2 * k + 1]);
        float m  = bf2f(s_OM[px_ * 32 + 18 + k]);
        int ki = k / 3, kj = k - ki * 3;
        float py  = (float)(h - 1 + ki) + dy;
        float pxf = (float)(px_ - 1 + kj) + dx;
        float y0f = floorf(py), x0f = floorf(pxf);
        float ly = py - y0f, lx = pxf - x0f;
        int iy0 = (int)y0f, ix0 = (int)x0f;
        int cy0 = min(max(iy0 + 1, 0), 65), cy1 = min(max(iy0 + 2, 0), 65);
        int cx0 = min(max(ix0 + 1, 0), 65), cx1 = min(max(ix0 + 2, 0), 65);
        int rb = b * 66 * 66;
        s_a0[0 * 576 + idx] = ((rb + cy0 * 66) + cx0) * 128;
        s_a0[1 * 576 + idx] = ((rb + cy0 * 66) + cx1) * 128;
        s_a0[2 * 576 + idx] = ((rb + cy1 * 66) + cx0) * 128;
        s_a0[3 * 576 + idx] = ((rb + cy1 * 66) + cx1) * 128;
        s_w0[0 * 576 + idx] = (1.f - ly) * (1.f - lx) * m;
        s_w0[1 * 576 + idx] = (1.f - ly) * lx * m;
        s_w0[2 * 576 + idx] = ly * (1.f - lx) * m;
        s_w0[3 * 576 + idx] = ly * lx * m;
    }
    __syncthreads();

    int wv = tid >> 6, lane = tid & 63, quad = lane >> 4, l16 = lane & 15;
    int ocq = wv & 3, ng = wv >> 2;
    int px = tid >> 3, cg2 = tid & 7;             // sampling role (all 512): 8 ch of one px

    int rowA0 = ocq * 32 + l16, rowA1 = rowA0 + 16;
    int offB0 = (ng * 32 + l16) * PADu + quad * 8;
    int offB1 = (ng * 32 + 16 + l16) * PADu + quad * 8;

    f32x4 acc00 = {0.f,0.f,0.f,0.f}, acc01 = {0.f,0.f,0.f,0.f};
    f32x4 acc10 = {0.f,0.f,0.f,0.f}, acc11 = {0.f,0.f,0.f,0.f};

    // pair j covers kc = 2j, 2j+1 -> same tap k = j>>1, channel half (j&1)*64
    auto loadP = [&](int j, ushort8& C0, ushort8& C1, ushort8& C2, ushort8& C3, float4& Wt){
        int k = j >> 1, cb = (j & 1) << 6;
        int idx = k * 64 + px;
        int co = cb + cg2 * 8;
        Wt.x = s_w0[0 * 576 + idx]; Wt.y = s_w0[1 * 576 + idx];
        Wt.z = s_w0[2 * 576 + idx]; Wt.w = s_w0[3 * 576 + idx];
        C0 = *(const ushort8*)(xTp + s_a0[0 * 576 + idx] + co);
        C1 = *(const ushort8*)(xTp + s_a0[1 * 576 + idx] + co);
        C2 = *(const ushort8*)(xTp + s_a0[2 * 576 + idx] + co);
        C3 = *(const ushort8*)(xTp + s_a0[3 * 576 + idx] + co);
    };
    auto bodyP = [&](int j, ushort8& C0, ushort8& C1, ushort8& C2, ushort8& C3, float4& Wt){
        int p = j & 1;
        unsigned short* sBp = sB + p * 5120;
        const unsigned short* wj = wAv + (size_t)(2 * j) * 4096 + quad * 1024;
        short8 a00 = *(const short8*)(wj + rowA0 * 8);
        short8 a01 = *(const short8*)(wj + rowA1 * 8);
        short8 a10 = *(const short8*)(wj + 4096 + rowA0 * 8);
        short8 a11 = *(const short8*)(wj + 4096 + rowA1 * 8);
        uint4v ov;
        #pragma unroll
        for (int q = 0; q < 4; q++){
            float v0 = Wt.x * bf2f(C0[2*q])   + Wt.y * bf2f(C1[2*q])
                     + Wt.z * bf2f(C2[2*q])   + Wt.w * bf2f(C3[2*q]);
            float v1 = Wt.x * bf2f(C0[2*q+1]) + Wt.y * bf2f(C1[2*q+1])
                     + Wt.z * bf2f(C2[2*q+1]) + Wt.w * bf2f(C3[2*q+1]);
            ov[q] = cvtpk_bf16(v0, v1);
        }
        *(uint4v*)(sBp + (cg2 >> 2) * 2560 + px * PADu + (cg2 & 3) * 8) = ov;
        if (j + 2 < 18) loadP(j + 2, C0, C1, C2, C3, Wt);   // 2-deep gather prefetch
        __syncthreads();
        short8 b0 = *(const short8*)(sBp + offB0);
        short8 b1 = *(const short8*)(sBp + offB1);
        acc00 = __builtin_amdgcn_mfma_f32_16x16x32_bf16(a00, b0, acc00, 0, 0, 0);
        acc01 = __builtin_amdgcn_mfma_f32_16x16x32_bf16(a00, b1, acc01, 0, 0, 0);
        acc10 = __builtin_amdgcn_mfma_f32_16x16x32_bf16(a01, b0, acc10, 0, 0, 0);
        acc11 = __builtin_amdgcn_mfma_f32_16x16x32_bf16(a01, b1, acc11, 0, 0, 0);
        b0 = *(const short8*)(sBp + 2560 + offB0);
        b1 = *(const short8*)(sBp + 2560 + offB1);
        acc00 = __builtin_amdgcn_mfma_f32_16x16x32_bf16(a10, b0, acc00, 0, 0, 0);
        acc01 = __builtin_amdgcn_mfma_f32_16x16x32_bf16(a10, b1, acc01, 0, 0, 0);
        acc10 = __builtin_amdgcn_mfma_f32_16x16x32_bf16(a11, b0, acc10, 0, 0, 0);
        acc11 = __builtin_amdgcn_mfma_f32_16x16x32_bf16(a11, b1, acc11, 0, 0, 0);
    };

    ushort8 C0a, C1a, C2a, C3a, C0b, C1b, C2b, C3b;
    float4 Wta, Wtb;
    loadP(0, C0a, C1a, C2a, C3a, Wta);
    loadP(1, C0b, C1b, C2b, C3b, Wtb);
    for (int jh = 0; jh < 9; jh++){
        bodyP(jh * 2,     C0a, C1a, C2a, C3a, Wta);
        bodyP(jh * 2 + 1, C0b, C1b, C2b, C3b, Wtb);
    }

    // ============== Epilogue A: stash y in LDS, accumulate BN partial sums ==============
    __syncthreads();
    float* ls = (float*)smem;   // [128][67] fp32 = 34304 B (overlaps tiles; done with them)
    #pragma unroll
    for (int to = 0; to < 2; to++){
        #pragma unroll
        for (int tn = 0; tn < 2; tn++){
            f32x4 a = to ? (tn ? acc11 : acc10) : (tn ? acc01 : acc00);
            int nl = ng * 32 + tn * 16 + l16;
            #pragma unroll
            for (int r = 0; r < 4; r++){
                int oc = ocq * 32 + to * 16 + quad * 4 + r;
                ls[oc * 67 + nl] = a[r] + b_reg[oc];
            }
        }
    }
    __syncthreads();
    if (tid < 128){
        int oc = tid;
        float s = 0.f, s2 = 0.f;
        #pragma unroll 8
        for (int nl = 0; nl < 64; nl++){
            float v = ls[oc * 67 + nl];
            s += v; s2 = fmaf(v, v, s2);
        }
        atomicAdd(&psum[oc], s);
        atomicAdd(&psum[128 + oc], s2);
    }

    // ============== Software grid barrier (all 512 blocks co-resident) ==================
    __syncthreads();   // compiler drains vmcnt before s_barrier -> psum adds complete
    if (tid == 0){
        __hip_atomic_fetch_add(bar, 1u, __ATOMIC_ACQ_REL, __HIP_MEMORY_SCOPE_AGENT);
        while (__hip_atomic_load(bar, __ATOMIC_ACQUIRE, __HIP_MEMORY_SCOPE_AGENT) < NBLK)
            __builtin_amdgcn_s_sleep(2);
    }
    __syncthreads();

    // ============== Epilogue B: BN finalize + affine + ReLU -> out ======================
    int oc2 = tid >> 2, q4 = tid & 3;
    float s  = __hip_atomic_load(&psum[oc2],       __ATOMIC_RELAXED, __HIP_MEMORY_SCOPE_AGENT);
    float s2 = __hip_atomic_load(&psum[128 + oc2], __ATOMIC_RELAXED, __HIP_MEMORY_SCOPE_AGENT);
    float mean = s * (1.f / 32768.f);
    float var  = s2 * (1.f / 32768.f) - mean * mean;
    float rs = rsqrtf(var + 1e-5f);
    float g = gamma[oc2] * rs;
    float bt = beta[oc2] - mean * g;
    float* op = out + (size_t)(b * 128 + oc2) * HWi + h * 64 + q4 * 16;
    const float* lr = ls + oc2 * 67 + q4 * 16;
    #pragma unroll
    for (int r = 0; r < 4; r++){
        float4 o;
        o.x = fmaxf(fmaf(lr[r * 4 + 0], g, bt), 0.f);
        o.y = fmaxf(fmaf(lr[r * 4 + 1], g, bt), 0.f);
        o.z = fmaxf(fmaf(lr[r * 4 + 2], g, bt), 0.f);
        o.w = fmaxf(fmaf(lr[r * 4 + 3], g, bt), 0.f);
        *(float4*)(op + r * 4) = o;
    }
}

extern "C" void kernel_launch(void* const* d_in, const int* in_sizes, int n_in,
                              void* d_out, int out_size, void* d_ws, size_t ws_size,
                              hipStream_t stream){
    const float* x     = (const float*)d_in[0];
    const float* w_off = (const float*)d_in[1];
    const float* b_off = (const float*)d_in[2];
    const float* w_mod = (const float*)d_in[3];
    const float* b_mod = (const float*)d_in[4];
    const float* w_reg = (const float*)d_in[5];
    const float* b_reg = (const float*)d_in[6];
    const float* gamma = (const float*)d_in[7];
    const float* beta  = (const float*)d_in[8];

    char* wsb = (char*)d_ws;
    unsigned short* xTp   = (unsigned short*)(wsb);                    // 8,921,088 B
    unsigned short* wAv   = (unsigned short*)(wsb + 19406848);         //   294,912 B
    unsigned short* w27A  = (unsigned short*)(wsb + 19701760);         //    73,728 B
    float*          biasom= (float*)(wsb + 19775488);                  //       128 B
    float*          psum  = (float*)(wsb + 19775616);                  //     1,024 B
    unsigned*       bar   = (unsigned*)(wsb + 19776640);               //         4 B
    float* out = (float*)d_out;

    hipLaunchKernelGGL(k_pre, dim3(1250), dim3(256), 0, stream, x, xTp, w_reg, w_off, w_mod, b_off, b_mod, wAv, w27A, biasom, psum, bar);
    hipLaunchKernelGGL(k_fused, dim3(512), dim3(512), 0, stream, xTp, w27A, biasom, wAv, b_reg, gamma, beta, out, psum, bar);
}

// Round 10
// 131.813 us; speedup vs baseline: 1.5787x; 1.5787x over previous
//
#include <hip/hip_runtime.h>
#include <math.h>

#define H 64
#define W 64
#define C 128
#define NB 8
#define COUT 128
#define HWi 4096
#define NKC 36
#define PADu 40          // LDS row pitch in ushorts (80B = 5 superbanks)

typedef __attribute__((ext_vector_type(8))) short short8;
typedef __attribute__((ext_vector_type(8))) unsigned short ushort8;
typedef __attribute__((ext_vector_type(4))) unsigned int uint4v;
typedef __attribute__((ext_vector_type(4))) float f32x4;

__device__ __forceinline__ unsigned short f2bf(float f){
    unsigned u = __float_as_uint(f);
    unsigned r = (u + 0x7FFFu + ((u >> 16) & 1u)) >> 16;
    return (unsigned short)r;
}
__device__ __forceinline__ float bf2f(unsigned short u){
    return __uint_as_float(((unsigned)u) << 16);
}
__device__ __forceinline__ unsigned cvtpk_bf16(float lo, float hi){
    unsigned r;
    asm("v_cvt_pk_bf16_f32 %0, %1, %2" : "=v"(r) : "v"(lo), "v"(hi));
    return r;
}

// ---------- k_pre: fused x-transpose + weight prep + psum zero ----------
// blocks [0,528): x NCHW fp32 -> zero-padded NHWC bf16 [8][66][66][128], XCD-affine batch=bid&7
//   transpose loads vectorized to float4 (16B/lane): 8 iters instead of 32 scalar loads.
// blocks [528,1250): wAv [kc][q4][r128][j8] (fragment-major), w27A [kc][q4][m32][t8],
//                    biasom, psum=0
__global__ void k_pre(const float* __restrict__ x, unsigned short* __restrict__ xTp,
                      const float* __restrict__ w_reg, const float* __restrict__ w_off,
                      const float* __restrict__ w_mod, const float* __restrict__ b_off,
                      const float* __restrict__ b_mod,
                      unsigned short* __restrict__ wAv, unsigned short* __restrict__ w27A,
                      float* __restrict__ biasom, float* __restrict__ psum){
    int tid = threadIdx.x;
    if (blockIdx.x >= 528){
        int i = (blockIdx.x - 528) * 256 + tid;
        if (i < 147456){
            int kc = i >> 12, rem = i & 4095;
            int q = rem >> 10, r = (rem >> 3) & 127, j = rem & 7;
            int kk = kc * 32 + q * 8 + j, k = kk >> 7, c = kk & 127;
            wAv[i] = f2bf(w_reg[r * 1152 + c * 9 + k]);
        } else if (i < 147456 + 36864){
            int j2 = i - 147456;
            int kc = j2 >> 10, rem = j2 & 1023;
            int q = rem >> 8, m = (rem >> 3) & 31, t = rem & 7;
            int kkl = q * 8 + t;
            int kk = kc * 32 + kkl, k = kk >> 7, c = kk & 127;
            float v = 0.f;
            if (m < 18) v = w_off[m * 1152 + c * 9 + k];
            else if (m < 27) v = w_mod[(m - 18) * 1152 + c * 9 + k];
            w27A[j2] = f2bf(v);
        } else if (i < 147456 + 36864 + 32){
            int m = i - 147456 - 36864;
            biasom[m] = (m < 18) ? b_off[m] : (m < 27 ? b_mod[m - 18] : 0.f);
        } else if (i < 147456 + 36864 + 32 + 256){
            psum[i - 147456 - 36864 - 32] = 0.f;
        }
        return;
    }
    int bidx = blockIdx.x;
    int b = bidx & 7, hp = bidx >> 3;       // XCD-affine: batch = bid%8
    unsigned short* row = xTp + (size_t)(b * 66 + hp) * 66 * 128;
    if (hp == 0 || hp == 65){
        ushort8 z = {0,0,0,0,0,0,0,0};
        for (int i = tid; i < 66 * 128 / 8; i += 256) ((ushort8*)row)[i] = z;
        return;
    }
    int h = hp - 1;
    __shared__ unsigned short s[64 * 136];
    // float4-vectorized gather: 2048 float4 total, 8 per thread (G13)
    #pragma unroll
    for (int it = 0; it < 8; it++){
        int idx = it * 256 + tid;
        int c = idx >> 4, w4 = (idx & 15) * 4;
        float4 v = *(const float4*)(x + (size_t)(b * 128 + c) * HWi + h * 64 + w4);
        s[(w4 + 0) * 136 + c] = f2bf(v.x);
        s[(w4 + 1) * 136 + c] = f2bf(v.y);
        s[(w4 + 2) * 136 + c] = f2bf(v.z);
        s[(w4 + 3) * 136 + c] = f2bf(v.w);
    }
    __syncthreads();
    if (tid < 32){
        ushort8 z = {0,0,0,0,0,0,0,0};
        int wp = (tid < 16) ? 0 : 65;
        int sg = tid & 15;
        *(ushort8*)(row + wp * 128 + sg * 8) = z;
    }
    for (int it = tid; it < 1024; it += 256){
        int w2 = it >> 4, sg = it & 15;
        *(ushort8*)(row + (w2 + 1) * 128 + sg * 8) = *(const ushort8*)(s + w2 * 136 + sg * 8);
    }
}

// ---------- k_fused: 27-conv (phase 1) + deformable conv GEMM (phase 2) ----------
// Round-6 proven structure: direct global A-fragments, cvt_pk bf16 pack, paired kc,
// 2-deep gather prefetch, ybf + psum outputs (BN finalized by k_apply).
__global__ __launch_bounds__(512, 4) void k_fused(const unsigned short* __restrict__ xTp,
        const unsigned short* __restrict__ w27A, const float* __restrict__ biasom,
        const unsigned short* __restrict__ wAv, const float* __restrict__ b_reg,
        unsigned short* __restrict__ ybf, float* __restrict__ psum){
    __shared__ char smem[38912];
    int tid = threadIdx.x;
    // XCD-affine swizzle: 512 blocks = 8 batches x 64 rows; batch (bid&7) -> XCD (bid&7)
    int lb = (blockIdx.x & 7) * 64 + (blockIdx.x >> 3);
    int n0 = lb * 64;
    int b = n0 >> 12, h = (n0 >> 6) & 63;

    // ================= Phase 1: offset/mod conv, K split across 2 groups =================
    {
        int grp = tid >> 8, gt = tid & 255;
        unsigned short* pB = (unsigned short*)(smem + grp * 10240);   // [2][64*PADu] per grp
        int wvg = gt >> 6, lane = gt & 63, quad = lane >> 4, l16 = lane & 15;
        int nl = gt >> 2, sg = gt & 3;
        f32x4 acc0 = {0.f,0.f,0.f,0.f}, acc1 = {0.f,0.f,0.f,0.f};
        int kc0 = grp * 18;
        auto p1load = [&](int i, ushort8& B8){
            int kc = kc0 + i;
            int k = kc >> 2, cb = (kc & 3) << 5;
            int ki = k / 3, kj = k - ki * 3;
            int rowi = (b * 66 + h + ki) * 66 + (nl + kj);
            B8 = *(const ushort8*)(xTp + (size_t)rowi * 128 + cb + sg * 8);
        };
        auto p1body = [&](int i, ushort8& B8){
            int p = i & 1;
            int kc = kc0 + i;
            const unsigned short* wj = w27A + kc * 1024 + quad * 256;
            short8 a0 = *(const short8*)(wj + l16 * 8);
            short8 a1 = *(const short8*)(wj + (16 + l16) * 8);
            *(ushort8*)(pB + p * 2560 + nl * PADu + sg * 8) = B8;
            if (i + 2 < 18) p1load(i + 2, B8);   // 2-deep prefetch
            __syncthreads();
            short8 bfrag = *(const short8*)(pB + p * 2560 + (wvg * 16 + l16) * PADu + quad * 8);
            acc0 = __builtin_amdgcn_mfma_f32_16x16x32_bf16(a0, bfrag, acc0, 0, 0, 0);
            acc1 = __builtin_amdgcn_mfma_f32_16x16x32_bf16(a1, bfrag, acc1, 0, 0, 0);
        };
        ushort8 rB0, rB1;
        p1load(0, rB0);
        p1load(1, rB1);
        for (int ih = 0; ih < 9; ih++){
            p1body(ih * 2,     rB0);
            p1body(ih * 2 + 1, rB1);
        }
        float* s_red = (float*)(smem + 20480);     // [64][32] fp32
        int npx = wvg * 16 + l16;
        if (grp == 1){
            #pragma unroll
            for (int t = 0; t < 2; t++){
                f32x4 a = t ? acc1 : acc0;
                #pragma unroll
                for (int r = 0; r < 4; r++)
                    s_red[npx * 32 + t * 16 + quad * 4 + r] = a[r];
            }
        }
        __syncthreads();
        if (grp == 0){
            unsigned short* s_OM = (unsigned short*)smem;  // [64][32] bf16 at [0,4096)
            #pragma unroll
            for (int t = 0; t < 2; t++){
                f32x4 a = t ? acc1 : acc0;
                #pragma unroll
                for (int r = 0; r < 4; r++){
                    int oc = t * 16 + quad * 4 + r;
                    float v = a[r] + s_red[npx * 32 + oc] + biasom[oc];
                    if (oc >= 18) v = 2.f / (1.f + expf(-v));
                    s_OM[npx * 32 + oc] = f2bf(v);
                }
            }
        }
        __syncthreads();
    }

    // ================= Phase 2: deformable sampling + 128-out GEMM (paired kc) ============
    unsigned short* sB = (unsigned short*)smem;              // [2][2][64*PADu] = 20480 B
    int*   s_a0 = (int*)(smem + 20480);                      // [4][576] = 9216 B
    float* s_w0 = (float*)(smem + 29696);                    // [4][576] = 9216 B (ends 38912)
    const unsigned short* s_OM = (const unsigned short*)smem;  // alias (prologue only)

    for (int idx = tid; idx < 576; idx += 512){
        int k = idx >> 6, px_ = idx & 63;
        float dy = bf2f(s_OM[px_ * 32 + 2 * k]);
        float dx = bf2f(s_OM[px_ * 32 + 2 * k + 1]);
        float m  = bf2f(s_OM[px_ * 32 + 18 + k]);
        int ki = k / 3, kj = k - ki * 3;
        float py  = (float)(h - 1 + ki) + dy;
        float pxf = (float)(px_ - 1 + kj) + dx;
        float y0f = floorf(py), x0f = floorf(pxf);
        float ly = py - y0f, lx = pxf - x0f;
        int iy0 = (int)y0f, ix0 = (int)x0f;
        int cy0 = min(max(iy0 + 1, 0), 65), cy1 = min(max(iy0 + 2, 0), 65);
        int cx0 = min(max(ix0 + 1, 0), 65), cx1 = min(max(ix0 + 2, 0), 65);
        int rb = b * 66 * 66;
        s_a0[0 * 576 + idx] = ((rb + cy0 * 66) + cx0) * 128;
        s_a0[1 * 576 + idx] = ((rb + cy0 * 66) + cx1) * 128;
        s_a0[2 * 576 + idx] = ((rb + cy1 * 66) + cx0) * 128;
        s_a0[3 * 576 + idx] = ((rb + cy1 * 66) + cx1) * 128;
        s_w0[0 * 576 + idx] = (1.f - ly) * (1.f - lx) * m;
        s_w0[1 * 576 + idx] = (1.f - ly) * lx * m;
        s_w0[2 * 576 + idx] = ly * (1.f - lx) * m;
        s_w0[3 * 576 + idx] = ly * lx * m;
    }
    __syncthreads();

    int wv = tid >> 6, lane = tid & 63, quad = lane >> 4, l16 = lane & 15;
    int ocq = wv & 3, ng = wv >> 2;
    int px = tid >> 3, cg2 = tid & 7;             // sampling role (all 512): 8 ch of one px

    int rowA0 = ocq * 32 + l16, rowA1 = rowA0 + 16;
    int offB0 = (ng * 32 + l16) * PADu + quad * 8;
    int offB1 = (ng * 32 + 16 + l16) * PADu + quad * 8;

    f32x4 acc00 = {0.f,0.f,0.f,0.f}, acc01 = {0.f,0.f,0.f,0.f};
    f32x4 acc10 = {0.f,0.f,0.f,0.f}, acc11 = {0.f,0.f,0.f,0.f};

    // pair j covers kc = 2j, 2j+1 -> same tap k = j>>1, channel half (j&1)*64
    auto loadP = [&](int j, ushort8& C0, ushort8& C1, ushort8& C2, ushort8& C3, float4& Wt){
        int k = j >> 1, cb = (j & 1) << 6;
        int idx = k * 64 + px;
        int co = cb + cg2 * 8;
        Wt.x = s_w0[0 * 576 + idx]; Wt.y = s_w0[1 * 576 + idx];
        Wt.z = s_w0[2 * 576 + idx]; Wt.w = s_w0[3 * 576 + idx];
        C0 = *(const ushort8*)(xTp + s_a0[0 * 576 + idx] + co);
        C1 = *(const ushort8*)(xTp + s_a0[1 * 576 + idx] + co);
        C2 = *(const ushort8*)(xTp + s_a0[2 * 576 + idx] + co);
        C3 = *(const ushort8*)(xTp + s_a0[3 * 576 + idx] + co);
    };
    auto bodyP = [&](int j, ushort8& C0, ushort8& C1, ushort8& C2, ushort8& C3, float4& Wt){
        int p = j & 1;
        unsigned short* sBp = sB + p * 5120;
        const unsigned short* wj = wAv + (size_t)(2 * j) * 4096 + quad * 1024;
        short8 a00 = *(const short8*)(wj + rowA0 * 8);
        short8 a01 = *(const short8*)(wj + rowA1 * 8);
        short8 a10 = *(const short8*)(wj + 4096 + rowA0 * 8);
        short8 a11 = *(const short8*)(wj + 4096 + rowA1 * 8);
        uint4v ov;
        #pragma unroll
        for (int q = 0; q < 4; q++){
            float v0 = Wt.x * bf2f(C0[2*q])   + Wt.y * bf2f(C1[2*q])
                     + Wt.z * bf2f(C2[2*q])   + Wt.w * bf2f(C3[2*q]);
            float v1 = Wt.x * bf2f(C0[2*q+1]) + Wt.y * bf2f(C1[2*q+1])
                     + Wt.z * bf2f(C2[2*q+1]) + Wt.w * bf2f(C3[2*q+1]);
            ov[q] = cvtpk_bf16(v0, v1);
        }
        *(uint4v*)(sBp + (cg2 >> 2) * 2560 + px * PADu + (cg2 & 3) * 8) = ov;
        if (j + 2 < 18) loadP(j + 2, C0, C1, C2, C3, Wt);   // 2-deep gather prefetch
        __syncthreads();
        short8 b0 = *(const short8*)(sBp + offB0);
        short8 b1 = *(const short8*)(sBp + offB1);
        acc00 = __builtin_amdgcn_mfma_f32_16x16x32_bf16(a00, b0, acc00, 0, 0, 0);
        acc01 = __builtin_amdgcn_mfma_f32_16x16x32_bf16(a00, b1, acc01, 0, 0, 0);
        acc10 = __builtin_amdgcn_mfma_f32_16x16x32_bf16(a01, b0, acc10, 0, 0, 0);
        acc11 = __builtin_amdgcn_mfma_f32_16x16x32_bf16(a01, b1, acc11, 0, 0, 0);
        b0 = *(const short8*)(sBp + 2560 + offB0);
        b1 = *(const short8*)(sBp + 2560 + offB1);
        acc00 = __builtin_amdgcn_mfma_f32_16x16x32_bf16(a10, b0, acc00, 0, 0, 0);
        acc01 = __builtin_amdgcn_mfma_f32_16x16x32_bf16(a10, b1, acc01, 0, 0, 0);
        acc10 = __builtin_amdgcn_mfma_f32_16x16x32_bf16(a11, b0, acc10, 0, 0, 0);
        acc11 = __builtin_amdgcn_mfma_f32_16x16x32_bf16(a11, b1, acc11, 0, 0, 0);
    };

    ushort8 C0a, C1a, C2a, C3a, C0b, C1b, C2b, C3b;
    float4 Wta, Wtb;
    loadP(0, C0a, C1a, C2a, C3a, Wta);
    loadP(1, C0b, C1b, C2b, C3b, Wtb);
    for (int jh = 0; jh < 9; jh++){
        bodyP(jh * 2,     C0a, C1a, C2a, C3a, Wta);
        bodyP(jh * 2 + 1, C0b, C1b, C2b, C3b, Wtb);
    }

    __syncthreads();
    float* ls = (float*)smem;   // [128][67] fp32 = 34304 B (overlaps tiles; done with them)
    int sp0 = h * 64;
    #pragma unroll
    for (int to = 0; to < 2; to++){
        #pragma unroll
        for (int tn = 0; tn < 2; tn++){
            f32x4 a = to ? (tn ? acc11 : acc10) : (tn ? acc01 : acc00);
            int nl = ng * 32 + tn * 16 + l16;
            #pragma unroll
            for (int r = 0; r < 4; r++){
                int oc = ocq * 32 + to * 16 + quad * 4 + r;
                float v = a[r] + b_reg[oc];
                ybf[(size_t)(b * 128 + oc) * HWi + sp0 + nl] = f2bf(v);
                ls[oc * 67 + nl] = v;
            }
        }
    }
    __syncthreads();
    if (tid < 128){
        int oc = tid;
        float s = 0.f, s2 = 0.f;
        #pragma unroll 8
        for (int nl = 0; nl < 64; nl++){
            float v = ls[oc * 67 + nl];
            s += v; s2 = fmaf(v, v, s2);
        }
        atomicAdd(&psum[oc], s);
        atomicAdd(&psum[128 + oc], s2);
    }
}

// ---------- k_apply: BN (stats inline from psum) + affine + relu -> fp32 ----------
__global__ void k_apply(const unsigned short* __restrict__ ybf, const float* __restrict__ psum,
                        const float* __restrict__ gamma, const float* __restrict__ beta,
                        float* __restrict__ out){
    int lb = ((int)blockIdx.x & 7) * 256 + ((int)blockIdx.x >> 3);
    int e8 = (lb * 256 + (int)threadIdx.x) * 8;
    int c = (e8 >> 12) & 127;
    ushort8 u = *(const ushort8*)(ybf + e8);
    float s = psum[c], s2 = psum[128 + c];
    float mean = s * (1.f / 32768.f);
    float var  = s2 * (1.f / 32768.f) - mean * mean;
    float rs = rsqrtf(var + 1e-5f);
    float g = gamma[c] * rs;
    float bt = beta[c] - mean * g;
    float4 lo, hi;
    lo.x = fmaxf(fmaf(bf2f(u[0]), g, bt), 0.f);
    lo.y = fmaxf(fmaf(bf2f(u[1]), g, bt), 0.f);
    lo.z = fmaxf(fmaf(bf2f(u[2]), g, bt), 0.f);
    lo.w = fmaxf(fmaf(bf2f(u[3]), g, bt), 0.f);
    hi.x = fmaxf(fmaf(bf2f(u[4]), g, bt), 0.f);
    hi.y = fmaxf(fmaf(bf2f(u[5]), g, bt), 0.f);
    hi.z = fmaxf(fmaf(bf2f(u[6]), g, bt), 0.f);
    hi.w = fmaxf(fmaf(bf2f(u[7]), g, bt), 0.f);
    *(float4*)(out + e8)     = lo;
    *(float4*)(out + e8 + 4) = hi;
}

extern "C" void kernel_launch(void* const* d_in, const int* in_sizes, int n_in,
                              void* d_out, int out_size, void* d_ws, size_t ws_size,
                              hipStream_t stream){
    const float* x     = (const float*)d_in[0];
    const float* w_off = (const float*)d_in[1];
    const float* b_off = (const float*)d_in[2];
    const float* w_mod = (const float*)d_in[3];
    const float* b_mod = (const float*)d_in[4];
    const float* w_reg = (const float*)d_in[5];
    const float* b_reg = (const float*)d_in[6];
    const float* gamma = (const float*)d_in[7];
    const float* beta  = (const float*)d_in[8];

    char* wsb = (char*)d_ws;
    unsigned short* xTp   = (unsigned short*)(wsb);                    // 8,921,088 B
    unsigned short* ybf   = (unsigned short*)(wsb + 11018240);         // 8,388,608 B
    unsigned short* wAv   = (unsigned short*)(wsb + 19406848);         //   294,912 B
    unsigned short* w27A  = (unsigned short*)(wsb + 19701760);         //    73,728 B
    float*          biasom= (float*)(wsb + 19775488);                  //       128 B
    float*          psum  = (float*)(wsb + 19775616);                  //     1,024 B
    float* out = (float*)d_out;

    hipLaunchKernelGGL(k_pre,   dim3(1250), dim3(256), 0, stream, x, xTp, w_reg, w_off, w_mod, b_off, b_mod, wAv, w27A, biasom, psum);
    hipLaunchKernelGGL(k_fused, dim3(512),  dim3(512), 0, stream, xTp, w27A, biasom, wAv, b_reg, ybf, psum);
    hipLaunchKernelGGL(k_apply, dim3(2048), dim3(256), 0, stream, ybf, psum, gamma, beta, out);
}